// Round 5
// baseline (295.026 us; speedup 1.0000x reference)
//
#include <hip/hip_runtime.h>
#include <hip/hip_bf16.h>
#include <hip/hip_fp16.h>
#include <math.h>

#define N_NODES 50000
#define E_EDGES 800000
#define NEG_SLOPE 0.2f
#define EPS 1e-16f
#define NB_SCAN ((N_NODES + 255) / 256)   // 196
#define GX1 ((N_NODES + 127) / 128)       // 391
#define LOG2E 1.44269504f

typedef _Float16 f16x8 __attribute__((ext_vector_type(8)));
typedef _Float16 f16x4 __attribute__((ext_vector_type(4)));
typedef _Float16 h2f   __attribute__((ext_vector_type(2)));
typedef float    f32x4 __attribute__((ext_vector_type(4)));
typedef float    f32x2 __attribute__((ext_vector_type(2)));

// fp32 dot-accumulate of an fp16 pair product: v_dot2_f32_f16 where available
__device__ __forceinline__ float dot2acc(h2f a, h2f b, float c) {
#if __has_builtin(__builtin_amdgcn_fdot2)
    return __builtin_amdgcn_fdot2(a, b, c, false);
#else
    return c + (float)a[0] * (float)b[0] + (float)a[1] * (float)b[1];
#endif
}

// packed leaky-relu: max(s, 0.2*s) elementwise (v_pk_mul + v_pk_max)
__device__ __forceinline__ h2f leaky2(h2f s) {
    h2f t = s * (_Float16)NEG_SLOPE;
    return __builtin_elementwise_max(s, t);
}

__device__ __forceinline__ h2f cvt_h2(float x, float y) {
    h2f r; r[0] = (_Float16)x; r[1] = (_Float16)y; return r;
}

__device__ __forceinline__ f32x2 cvt2f(h2f x) {
    f32x2 r; r[0] = (float)x[0]; r[1] = (float)x[1]; return r;
}

// ---------------------------------------------------------------------------
// DPP rotation-add reduce: full 16-lane-row sum broadcast to all lanes of the
// row in 4 single-VALU v_add_f32_dpp ops (no LDS-pipe ds_swizzle).
// ---------------------------------------------------------------------------
template <int CTRL>
__device__ __forceinline__ float dpp_ror_add(float v) {
    const int t = __builtin_amdgcn_update_dpp(
        0, __float_as_int(v), CTRL, 0xf, 0xf, true);
    return v + __int_as_float(t);
}
__device__ __forceinline__ float red16(float v) {
    v = dpp_ror_add<0x128>(v);   // ror:8
    v = dpp_ror_add<0x124>(v);   // ror:4
    v = dpp_ror_add<0x122>(v);   // ror:2
    v = dpp_ror_add<0x121>(v);   // ror:1
    return v;
}

// load 8 contiguous elements as f16x8, converting if input is fp32
__device__ __forceinline__ f16x8 load8(const float* p) {
    const float4 v0 = *(const float4*)p;
    const float4 v1 = *(const float4*)(p + 4);
    f16x8 r;
    r[0] = (_Float16)v0.x; r[1] = (_Float16)v0.y;
    r[2] = (_Float16)v0.z; r[3] = (_Float16)v0.w;
    r[4] = (_Float16)v1.x; r[5] = (_Float16)v1.y;
    r[6] = (_Float16)v1.z; r[7] = (_Float16)v1.w;
    return r;
}
__device__ __forceinline__ f16x8 load8(const _Float16* p) {
    return *(const f16x8*)p;
}

// ---------------------------------------------------------------------------
// MFMA GEMM (fp16 compute, fp32 accum): Y[N, M2] = X[N,K] @ Wt[M2,K]^T,
// fp16 output. 128x256 tile, BK=32, 4 waves, 4x8 MFMA tiles/wave.
// R19: operand-swapped MFMA (A-op <- W rows, B-op <- X rows) so the C
// fragment's 4-reg run spans 4 consecutive Y COLUMNS of one row ->
// epilogue is 32 packed 8-byte stores/thread instead of 128 2-byte stores.
// ---------------------------------------------------------------------------
template <typename IT>
__global__ __launch_bounds__(256, 2)
void gemm_mfma(const IT* __restrict__ X, const __half* __restrict__ Wth,
               __half* __restrict__ Y, int Nrows, int K, int M2)
{
    const _Float16* Wt = (const _Float16*)Wth;
    _Float16* Yh = (_Float16*)Y;
    __shared__ _Float16 As[128][40];
    __shared__ _Float16 Bs[256][40];
    const int tid  = threadIdx.x;
    const int row0 = blockIdx.x * 128;
    const int col0 = blockIdx.y * 256;
    const int lane = tid & 63;
    const int wv   = tid >> 6;
    const int wr   = (wv >> 1) * 64;
    const int wc   = (wv & 1) * 128;
    const int fm   = lane & 15;
    const int fk   = (lane >> 4) * 8;
    const int quad = lane >> 4;

    f32x4 acc[4][8] = {};

    for (int k0 = 0; k0 < K; k0 += 32) {
        #pragma unroll
        for (int p = 0; p < 2; ++p) {
            const int idx = tid + p * 256;
            const int r = idx >> 2;
            const int c = (idx & 3) * 8;
            const int gr = row0 + r;
            f16x8 v = {};
            if (gr < Nrows)
                v = load8(X + (size_t)gr * K + k0 + c);
            *(f16x8*)&As[r][c] = v;
        }
        #pragma unroll
        for (int p = 0; p < 4; ++p) {
            const int idx = tid + p * 256;
            const int r = idx >> 2;
            const int c = (idx & 3) * 8;
            *(f16x8*)&Bs[r][c] = *(const f16x8*)(Wt + (size_t)(col0 + r) * K + k0 + c);
        }
        __syncthreads();

        f16x8 bf[8];
        #pragma unroll
        for (int j = 0; j < 8; ++j)
            bf[j] = *(const f16x8*)&Bs[wc + j * 16 + fm][fk];
        #pragma unroll
        for (int i = 0; i < 4; ++i) {
            const f16x8 af = *(const f16x8*)&As[wr + i * 16 + fm][fk];
            #pragma unroll
            for (int j = 0; j < 8; ++j)
                acc[i][j] = __builtin_amdgcn_mfma_f32_16x16x32_f16(bf[j], af, acc[i][j], 0, 0, 0);
        }
        __syncthreads();
    }

    // C' layout (operand-swapped): Y row = row0+wr+i*16+fm,
    //                              Y col = col0+wc+j*16+quad*4+rg
    #pragma unroll
    for (int i = 0; i < 4; ++i) {
        const int row = row0 + wr + i * 16 + fm;
        if (row < Nrows) {
            #pragma unroll
            for (int j = 0; j < 8; ++j) {
                const int col = col0 + wc + j * 16 + quad * 4;
                f16x4 v;
                v[0] = (_Float16)acc[i][j][0];
                v[1] = (_Float16)acc[i][j][1];
                v[2] = (_Float16)acc[i][j][2];
                v[3] = (_Float16)acc[i][j][3];
                *(f16x4*)(Yh + (size_t)row * M2 + col) = v;
            }
        }
    }
}

// ---------------------------------------------------------------------------
// Fused: weight-pair fp16 transpose convert (blocks 0..511) + dst histogram.
// R18: histogram also records each edge's arrival rank (the returned old
// count) so the scatter pass needs NO atomics.
// ---------------------------------------------------------------------------
#define CVT_BLOCKS 512   // (512*128 + 256*256) / 256
__global__ __launch_bounds__(256)
void cvt_and_hist(const float* __restrict__ Wl1, const float* __restrict__ Wr1,
                  const float* __restrict__ Wl2, const float* __restrict__ Wr2,
                  __half* __restrict__ W1t, __half* __restrict__ W2t,
                  const int* __restrict__ dst, int* __restrict__ deg,
                  int* __restrict__ erank)
{
    const int b = blockIdx.x;
    if (b < CVT_BLOCKS) {
        int id = b * 256 + threadIdx.x;
        if (id < 512 * 128) {
            const int n = id >> 7, k = id & 127;          // K=128, M=256
            const float* W = (n < 256) ? Wl1 : Wr1;
            const int nn = (n < 256) ? n : n - 256;
            W1t[id] = __float2half(W[(size_t)k * 256 + nn]);
        } else {
            id -= 512 * 128;
            const int n = id >> 8, k = id & 255;          // K=256, M=128
            const float* W = (n < 128) ? Wl2 : Wr2;
            const int nn = (n < 128) ? n : n - 128;
            W2t[id] = __float2half(W[(size_t)k * 128 + nn]);
        }
    } else {
        const int i = (b - CVT_BLOCKS) * 256 + threadIdx.x;
        if (i < E_EDGES) {
            const int r = atomicAdd(&deg[dst[i]], 1);
            erank[i] = r;
        }
    }
}

// ---------------------------------------------------------------------------
// Two-phase parallel scan (R11 proven).
// ---------------------------------------------------------------------------
__global__ __launch_bounds__(256)
void scan_local(const int* __restrict__ deg, int* __restrict__ locpre,
                int* __restrict__ blockSum)
{
    const int i = blockIdx.x * 256 + threadIdx.x;
    const int lane = threadIdx.x & 63;
    const int wid = threadIdx.x >> 6;
    const int val = (i < N_NODES) ? deg[i] : 0;

    int v = val;
    #pragma unroll
    for (int off = 1; off < 64; off <<= 1) {
        int t = __shfl_up(v, off, 64);
        if (lane >= off) v += t;
    }
    __shared__ int ws[4];
    if (lane == 63) ws[wid] = v;
    __syncthreads();
    int woff = 0;
    for (int k = 0; k < wid; ++k) woff += ws[k];
    if (i < N_NODES) locpre[i] = woff + v - val;
    if (threadIdx.x == 255) blockSum[blockIdx.x] = woff + v;
}

__global__ __launch_bounds__(256)
void scan_final(const int* __restrict__ locpre, const int* __restrict__ blockSum,
                int* __restrict__ rowptr)
{
    const int b = blockIdx.x;
    const int t = threadIdx.x;
    int v = (t < b) ? blockSum[t] : 0;          // NB_SCAN(=196) < 256
    #pragma unroll
    for (int off = 32; off; off >>= 1) v += __shfl_xor(v, off, 64);
    __shared__ int ws[4];
    if ((t & 63) == 0) ws[t >> 6] = v;
    __syncthreads();
    const int offset = ws[0] + ws[1] + ws[2] + ws[3];

    const int i = b * 256 + t;
    if (i < N_NODES)
        rowptr[i] = locpre[i] + offset;
    if (b == 0 && t == 0) rowptr[N_NODES] = E_EDGES;
}

// ---------------------------------------------------------------------------
// R18: atomic-free scatter. pos = rowptr[dst] + rank (rank recorded in the
// histogram pass). rowptr is 200 KB -> L2-resident gather.
// ---------------------------------------------------------------------------
__global__ __launch_bounds__(256)
void scatter_edges(const int* __restrict__ src, const int* __restrict__ dst,
                   const int* __restrict__ rowptr, const int* __restrict__ erank,
                   int* __restrict__ ssrc, int E)
{
    int i = blockIdx.x * blockDim.x + threadIdx.x;
    if (i < E) {
        const int pos = rowptr[dst[i]] + erank[i];
        ssrc[pos] = src[i];
    }
}

// ---------------------------------------------------------------------------
// Layer-1 aggregation (H=4, C=64) — R17 shape: 8-edge unroll, pk-fp32
// accumulate, scalar CSR path (readfirstlane), DPP row reduce, exp2.
// Pinned at ~63 us by the L2-miss gather pipe (3.45 TB/s invariant R16-R18).
// ---------------------------------------------------------------------------
__global__ __launch_bounds__(256)
void agg1(const __half* __restrict__ xlr, const int* __restrict__ rowptr,
          const int* __restrict__ ssrc, const float* __restrict__ att,
          const float* __restrict__ b, __half* __restrict__ h)
{
    const int w = __builtin_amdgcn_readfirstlane(
        (int)((blockIdx.x * blockDim.x + threadIdx.x) >> 6));
    if (w >= N_NODES) return;
    const int lane = threadIdx.x & 63;
    const int ch = lane * 4;

    const float4 atf = *(const float4*)(att + ch);
    const h2f at0 = cvt_h2(atf.x * LOG2E, atf.y * LOG2E);
    const h2f at1 = cvt_h2(atf.z * LOG2E, atf.w * LOG2E);
    const float4 bb = *(const float4*)(b + ch);
    union { uint2 u; h2f v[2]; } R;
    R.u = *(const uint2*)(xlr + (size_t)w * 512 + 256 + ch);
    const h2f r0 = R.v[0], r1 = R.v[1];

    f32x2 a01 = {0.f, 0.f}, a23 = {0.f, 0.f};
    f32x2 den2 = {0.f, 0.f};

    const int beg = rowptr[w], end = rowptr[w + 1];
    int i = beg;
    while (i + 8 <= end) {
        union { uint2 u; h2f v[2]; } U[8];
        #pragma unroll
        for (int j = 0; j < 8; ++j) {
            const int s = ssrc[i + j];
            U[j].u = *(const uint2*)(xlr + (size_t)s * 512 + ch);
        }
        float m[8];
        #pragma unroll
        for (int j = 0; j < 8; ++j) {
            m[j] = dot2acc(leaky2(U[j].v[0] + r0), at0, 0.f);
            m[j] = dot2acc(leaky2(U[j].v[1] + r1), at1, m[j]);
        }
        #pragma unroll
        for (int j = 0; j < 8; ++j)
            m[j] = red16(m[j]);
        float e[8];
        #pragma unroll
        for (int j = 0; j < 8; ++j)
            e[j] = exp2f(m[j]);
        #pragma unroll
        for (int j = 0; j < 8; j += 2) {
            f32x2 ep = {e[j], e[j + 1]};
            den2 += ep;
        }
        #pragma unroll
        for (int j = 0; j < 8; ++j) {
            const f32x2 ee = {e[j], e[j]};
            a01 += ee * cvt2f(U[j].v[0]);
            a23 += ee * cvt2f(U[j].v[1]);
        }
        i += 8;
    }
    while (i + 4 <= end) {
        union { uint2 u; h2f v[2]; } U[4];
        #pragma unroll
        for (int j = 0; j < 4; ++j) {
            const int s = ssrc[i + j];
            U[j].u = *(const uint2*)(xlr + (size_t)s * 512 + ch);
        }
        float m[4];
        #pragma unroll
        for (int j = 0; j < 4; ++j) {
            m[j] = dot2acc(leaky2(U[j].v[0] + r0), at0, 0.f);
            m[j] = dot2acc(leaky2(U[j].v[1] + r1), at1, m[j]);
        }
        #pragma unroll
        for (int j = 0; j < 4; ++j)
            m[j] = red16(m[j]);
        float e[4];
        #pragma unroll
        for (int j = 0; j < 4; ++j)
            e[j] = exp2f(m[j]);
        den2 += (f32x2){e[0], e[1]};
        den2 += (f32x2){e[2], e[3]};
        #pragma unroll
        for (int j = 0; j < 4; ++j) {
            const f32x2 ee = {e[j], e[j]};
            a01 += ee * cvt2f(U[j].v[0]);
            a23 += ee * cvt2f(U[j].v[1]);
        }
        i += 4;
    }
    while (i < end) {
        const int s = ssrc[i];
        union { uint2 u; h2f v[2]; } U;
        U.u = *(const uint2*)(xlr + (size_t)s * 512 + ch);
        float m = dot2acc(leaky2(U.v[0] + r0), at0, 0.f);
        m = dot2acc(leaky2(U.v[1] + r1), at1, m);
        m = red16(m);
        const float e = exp2f(m);
        den2[0] += e;
        const f32x2 ee = {e, e};
        a01 += ee * cvt2f(U.v[0]);
        a23 += ee * cvt2f(U.v[1]);
        ++i;
    }

    const float den = den2[0] + den2[1];
    const float inv = 1.f / (den + EPS);
    float v0 = a01[0] * inv + bb.x;
    float v1 = a01[1] * inv + bb.y;
    float v2 = a23[0] * inv + bb.z;
    float v3 = a23[1] * inv + bb.w;
    v0 = v0 > 0.f ? v0 : __expf(v0) - 1.f;
    v1 = v1 > 0.f ? v1 : __expf(v1) - 1.f;
    v2 = v2 > 0.f ? v2 : __expf(v2) - 1.f;
    v3 = v3 > 0.f ? v3 : __expf(v3) - 1.f;
    union { uint2 u; __half2 h2[2]; } O;
    O.h2[0] = __floats2half2_rn(v0, v1);
    O.h2[1] = __floats2half2_rn(v2, v3);
    *(uint2*)(h + (size_t)w * 256 + ch) = O.u;
}

// ---------------------------------------------------------------------------
// Layer-2 aggregation (H=1, C=128) — R17 shape: 4-edge-per-half main loop,
// pk-fp32 accumulate. 2-edge + 1-edge tails.
// ---------------------------------------------------------------------------
__global__ __launch_bounds__(256)
void agg2(const __half* __restrict__ xlr, const int* __restrict__ rowptr,
          const int* __restrict__ ssrc, const float* __restrict__ att,
          const float* __restrict__ b, float* __restrict__ out)
{
    const int w = __builtin_amdgcn_readfirstlane(
        (int)((blockIdx.x * blockDim.x + threadIdx.x) >> 6));
    if (w >= N_NODES) return;
    const int lane = threadIdx.x & 63;
    const int half = lane >> 5;
    const int ch = (lane & 31) * 4;

    const float4 atf = *(const float4*)(att + ch);
    const h2f at0 = cvt_h2(atf.x * LOG2E, atf.y * LOG2E);
    const h2f at1 = cvt_h2(atf.z * LOG2E, atf.w * LOG2E);
    const float4 bb = *(const float4*)(b + ch);
    union { uint2 u; h2f v[2]; } R;
    R.u = *(const uint2*)(xlr + (size_t)w * 256 + 128 + ch);
    const h2f r0 = R.v[0], r1 = R.v[1];

    f32x2 a01 = {0.f, 0.f}, a23 = {0.f, 0.f};
    float den = 0.f;

    const int beg = rowptr[w], end = rowptr[w + 1];
    int i = beg + half;
    while (i + 6 < end) {
        union { uint2 u; h2f v[2]; } U[4];
        #pragma unroll
        for (int j = 0; j < 4; ++j) {
            const int s = ssrc[i + 2 * j];
            U[j].u = *(const uint2*)(xlr + (size_t)s * 256 + ch);
        }
        float m[4];
        #pragma unroll
        for (int j = 0; j < 4; ++j) {
            m[j] = dot2acc(leaky2(U[j].v[0] + r0), at0, 0.f);
            m[j] = dot2acc(leaky2(U[j].v[1] + r1), at1, m[j]);
        }
        #pragma unroll
        for (int j = 0; j < 4; ++j) {
            m[j] = red16(m[j]);
            m[j] += __shfl_xor(m[j], 16, 64);
        }
        #pragma unroll
        for (int j = 0; j < 4; ++j) {
            const float e = exp2f(m[j]);
            den += e;
            const f32x2 ee = {e, e};
            a01 += ee * cvt2f(U[j].v[0]);
            a23 += ee * cvt2f(U[j].v[1]);
        }
        i += 8;
    }
    while (i + 2 < end) {
        union { uint2 u; h2f v[2]; } U[2];
        #pragma unroll
        for (int j = 0; j < 2; ++j) {
            const int s = ssrc[i + 2 * j];
            U[j].u = *(const uint2*)(xlr + (size_t)s * 256 + ch);
        }
        float m[2];
        #pragma unroll
        for (int j = 0; j < 2; ++j) {
            m[j] = dot2acc(leaky2(U[j].v[0] + r0), at0, 0.f);
            m[j] = dot2acc(leaky2(U[j].v[1] + r1), at1, m[j]);
        }
        #pragma unroll
        for (int j = 0; j < 2; ++j) {
            m[j] = red16(m[j]);
            m[j] += __shfl_xor(m[j], 16, 64);
        }
        #pragma unroll
        for (int j = 0; j < 2; ++j) {
            const float e = exp2f(m[j]);
            den += e;
            const f32x2 ee = {e, e};
            a01 += ee * cvt2f(U[j].v[0]);
            a23 += ee * cvt2f(U[j].v[1]);
        }
        i += 4;
    }
    if (i < end) {
        const int s = ssrc[i];
        union { uint2 u; h2f v[2]; } U;
        U.u = *(const uint2*)(xlr + (size_t)s * 256 + ch);
        float m = dot2acc(leaky2(U.v[0] + r0), at0, 0.f);
        m = dot2acc(leaky2(U.v[1] + r1), at1, m);
        m = red16(m);
        m += __shfl_xor(m, 16, 64);
        const float e = exp2f(m);
        den += e;
        const f32x2 ee = {e, e};
        a01 += ee * cvt2f(U.v[0]);
        a23 += ee * cvt2f(U.v[1]);
    }

    a01[0] += __shfl_xor(a01[0], 32, 64);
    a01[1] += __shfl_xor(a01[1], 32, 64);
    a23[0] += __shfl_xor(a23[0], 32, 64);
    a23[1] += __shfl_xor(a23[1], 32, 64);
    den += __shfl_xor(den, 32, 64);

    if (half == 0) {
        const float inv = 1.f / (den + EPS);
        float4 o;
        o.x = a01[0] * inv + bb.x;
        o.y = a01[1] * inv + bb.y;
        o.z = a23[0] * inv + bb.z;
        o.w = a23[1] * inv + bb.w;
        *(float4*)(out + (size_t)w * 128 + ch) = o;
    }
}

extern "C" void kernel_launch(void* const* d_in, const int* in_sizes, int n_in,
                              void* d_out, int out_size, void* d_ws, size_t ws_size,
                              hipStream_t stream)
{
    const float* x    = (const float*)d_in[0];
    const int*   ei   = (const int*)d_in[1];
    const float* Wl1  = (const float*)d_in[2];
    const float* Wr1  = (const float*)d_in[3];
    const float* att1 = (const float*)d_in[4];
    const float* b1   = (const float*)d_in[5];
    const float* Wl2  = (const float*)d_in[6];
    const float* Wr2  = (const float*)d_in[7];
    const float* att2 = (const float*)d_in[8];
    const float* b2   = (const float*)d_in[9];
    const int* src = ei;
    const int* dst = ei + E_EDGES;
    float* out = (float*)d_out;

    // Workspace layout (fp16 unless noted):
    //   xlr1 [N,512] = [xl1|xr1]   (51.2 MB); reused as xlr2 [N,256]
    //   hh   [N,256]  — ALSO overlaid as erank[E] (lifetimes disjoint:
    //                   erank dies at scatter_edges; hh born at agg1)
    //   W1t  [512,128], W2t [256,256]
    //   ints: rowptr[N+1], deg[N], ssrc[E], locpre[N], blockSum[NB]
    __half* xlr1 = (__half*)d_ws;
    __half* hh   = xlr1 + (size_t)N_NODES * 512;
    __half* W1t  = hh + (size_t)N_NODES * 256;
    __half* W2t  = W1t + 512 * 128;
    int* rowptr   = (int*)(W2t + 256 * 256);
    int* deg      = rowptr + (N_NODES + 1);
    int* ssrc     = deg + N_NODES;
    int* locpre   = ssrc + E_EDGES;
    int* blockSum = locpre + N_NODES;
    int* erank    = (int*)hh;           // overlay, 3.2 MB < 25.6 MB
    __half* xlr2 = xlr1;

    const dim3 blk(256);
    const int hist_blocks = (E_EDGES + 255) / 256;

    // --- zero deg ---
    hipMemsetAsync(deg, 0, (size_t)N_NODES * 4, stream);

    // --- weight convert + dst histogram w/ rank record ---
    cvt_and_hist<<<CVT_BLOCKS + hist_blocks, blk, 0, stream>>>(
        Wl1, Wr1, Wl2, Wr2, W1t, W2t, dst, deg, erank);

    // --- two-phase scan (R11 proven) ---
    scan_local<<<NB_SCAN, blk, 0, stream>>>(deg, locpre, blockSum);
    scan_final<<<NB_SCAN, blk, 0, stream>>>(locpre, blockSum, rowptr);

    // --- atomic-free edge scatter ---
    scatter_edges<<<hist_blocks, blk, 0, stream>>>(src, dst, rowptr, erank, ssrc, E_EDGES);

    // --- Layer 1: [N,128] @ [128,512] (fused Wl|Wr), 128x256 tiles, BK=32 ---
    gemm_mfma<float><<<dim3(GX1, 2), blk, 0, stream>>>(x, W1t, xlr1, N_NODES, 128, 512);
    agg1<<<(N_NODES * 64 + 255) / 256, blk, 0, stream>>>(xlr1, rowptr, ssrc, att1, b1, hh);

    // --- Layer 2: [N,256] @ [256,256] (fused Wl|Wr), 128x256 tiles, BK=32 ---
    gemm_mfma<_Float16><<<dim3(GX1, 1), blk, 0, stream>>>((const _Float16*)hh, W2t, xlr2, N_NODES, 256, 256);
    agg2<<<(N_NODES * 64 + 255) / 256, blk, 0, stream>>>(xlr2, rowptr, ssrc, att2, b2, out);
}

// Round 7
// 281.903 us; speedup vs baseline: 1.0466x; 1.0466x over previous
//
#include <hip/hip_runtime.h>
#include <hip/hip_bf16.h>
#include <hip/hip_fp16.h>
#include <math.h>

#define N_NODES 50000
#define E_EDGES 800000
#define NEG_SLOPE 0.2f
#define EPS 1e-16f
#define NB_SCAN ((N_NODES + 255) / 256)   // 196
#define GX1 ((N_NODES + 127) / 128)       // 391
#define LOG2E 1.44269504f

typedef _Float16 f16x8 __attribute__((ext_vector_type(8)));
typedef _Float16 h2f   __attribute__((ext_vector_type(2)));
typedef float    f32x4 __attribute__((ext_vector_type(4)));
typedef float    f32x2 __attribute__((ext_vector_type(2)));

// fp32 dot-accumulate of an fp16 pair product: v_dot2_f32_f16 where available
__device__ __forceinline__ float dot2acc(h2f a, h2f b, float c) {
#if __has_builtin(__builtin_amdgcn_fdot2)
    return __builtin_amdgcn_fdot2(a, b, c, false);
#else
    return c + (float)a[0] * (float)b[0] + (float)a[1] * (float)b[1];
#endif
}

// packed leaky-relu: max(s, 0.2*s) elementwise (v_pk_mul + v_pk_max)
__device__ __forceinline__ h2f leaky2(h2f s) {
    h2f t = s * (_Float16)NEG_SLOPE;
    return __builtin_elementwise_max(s, t);
}

__device__ __forceinline__ h2f cvt_h2(float x, float y) {
    h2f r; r[0] = (_Float16)x; r[1] = (_Float16)y; return r;
}

__device__ __forceinline__ f32x2 cvt2f(h2f x) {
    f32x2 r; r[0] = (float)x[0]; r[1] = (float)x[1]; return r;
}

// ---------------------------------------------------------------------------
// DPP rotation-add reduce: full 16-lane-row sum broadcast to all lanes of the
// row in 4 single-VALU v_add_f32_dpp ops (no LDS-pipe ds_swizzle).
// ---------------------------------------------------------------------------
template <int CTRL>
__device__ __forceinline__ float dpp_ror_add(float v) {
    const int t = __builtin_amdgcn_update_dpp(
        0, __float_as_int(v), CTRL, 0xf, 0xf, true);
    return v + __int_as_float(t);
}
__device__ __forceinline__ float red16(float v) {
    v = dpp_ror_add<0x128>(v);   // ror:8
    v = dpp_ror_add<0x124>(v);   // ror:4
    v = dpp_ror_add<0x122>(v);   // ror:2
    v = dpp_ror_add<0x121>(v);   // ror:1
    return v;
}

// load 8 contiguous elements as f16x8, converting if input is fp32
__device__ __forceinline__ f16x8 load8(const float* p) {
    const float4 v0 = *(const float4*)p;
    const float4 v1 = *(const float4*)(p + 4);
    f16x8 r;
    r[0] = (_Float16)v0.x; r[1] = (_Float16)v0.y;
    r[2] = (_Float16)v0.z; r[3] = (_Float16)v0.w;
    r[4] = (_Float16)v1.x; r[5] = (_Float16)v1.y;
    r[6] = (_Float16)v1.z; r[7] = (_Float16)v1.w;
    return r;
}
__device__ __forceinline__ f16x8 load8(const _Float16* p) {
    return *(const f16x8*)p;
}

// ---------------------------------------------------------------------------
// MFMA GEMM (fp16 compute, fp32 accum): Y[N, M2] = X[N,K] @ Wt[M2,K]^T,
// fp16 output. 128x256 tile, BK=32, 4 waves, 4x8 MFMA tiles/wave.
// R20: R19 operand-swap REVERTED (regressed +11 us — segment count per byte
// was unchanged; the swap only rearranged, not improved, coalescing).
// ---------------------------------------------------------------------------
template <typename IT>
__global__ __launch_bounds__(256, 2)
void gemm_mfma(const IT* __restrict__ X, const __half* __restrict__ Wth,
               __half* __restrict__ Y, int Nrows, int K, int M2)
{
    const _Float16* Wt = (const _Float16*)Wth;
    __shared__ _Float16 As[128][40];
    __shared__ _Float16 Bs[256][40];
    const int tid  = threadIdx.x;
    const int row0 = blockIdx.x * 128;
    const int col0 = blockIdx.y * 256;
    const int lane = tid & 63;
    const int wv   = tid >> 6;
    const int wr   = (wv >> 1) * 64;
    const int wc   = (wv & 1) * 128;
    const int fm   = lane & 15;
    const int fk   = (lane >> 4) * 8;
    const int quad = lane >> 4;

    f32x4 acc[4][8] = {};

    for (int k0 = 0; k0 < K; k0 += 32) {
        #pragma unroll
        for (int p = 0; p < 2; ++p) {
            const int idx = tid + p * 256;
            const int r = idx >> 2;
            const int c = (idx & 3) * 8;
            const int gr = row0 + r;
            f16x8 v = {};
            if (gr < Nrows)
                v = load8(X + (size_t)gr * K + k0 + c);
            *(f16x8*)&As[r][c] = v;
        }
        #pragma unroll
        for (int p = 0; p < 4; ++p) {
            const int idx = tid + p * 256;
            const int r = idx >> 2;
            const int c = (idx & 3) * 8;
            *(f16x8*)&Bs[r][c] = *(const f16x8*)(Wt + (size_t)(col0 + r) * K + k0 + c);
        }
        __syncthreads();

        f16x8 bf[8];
        #pragma unroll
        for (int j = 0; j < 8; ++j)
            bf[j] = *(const f16x8*)&Bs[wc + j * 16 + fm][fk];
        #pragma unroll
        for (int i = 0; i < 4; ++i) {
            const f16x8 af = *(const f16x8*)&As[wr + i * 16 + fm][fk];
            #pragma unroll
            for (int j = 0; j < 8; ++j)
                acc[i][j] = __builtin_amdgcn_mfma_f32_16x16x32_f16(af, bf[j], acc[i][j], 0, 0, 0);
        }
        __syncthreads();
    }

    #pragma unroll
    for (int i = 0; i < 4; ++i) {
        #pragma unroll
        for (int j = 0; j < 8; ++j) {
            const int col = col0 + wc + j * 16 + fm;
            #pragma unroll
            for (int rg = 0; rg < 4; ++rg) {
                const int row = row0 + wr + i * 16 + quad * 4 + rg;
                if (row < Nrows)
                    Y[(size_t)row * M2 + col] = __float2half(acc[i][j][rg]);
            }
        }
    }
}

// ---------------------------------------------------------------------------
// Fused: weight-pair fp16 transpose convert (blocks 0..511) + dst histogram.
// R18: histogram also records each edge's arrival rank (the returned old
// count) so the scatter pass needs NO atomics.
// ---------------------------------------------------------------------------
#define CVT_BLOCKS 512   // (512*128 + 256*256) / 256
__global__ __launch_bounds__(256)
void cvt_and_hist(const float* __restrict__ Wl1, const float* __restrict__ Wr1,
                  const float* __restrict__ Wl2, const float* __restrict__ Wr2,
                  __half* __restrict__ W1t, __half* __restrict__ W2t,
                  const int* __restrict__ dst, int* __restrict__ deg,
                  int* __restrict__ erank)
{
    const int b = blockIdx.x;
    if (b < CVT_BLOCKS) {
        int id = b * 256 + threadIdx.x;
        if (id < 512 * 128) {
            const int n = id >> 7, k = id & 127;          // K=128, M=256
            const float* W = (n < 256) ? Wl1 : Wr1;
            const int nn = (n < 256) ? n : n - 256;
            W1t[id] = __float2half(W[(size_t)k * 256 + nn]);
        } else {
            id -= 512 * 128;
            const int n = id >> 8, k = id & 255;          // K=256, M=128
            const float* W = (n < 128) ? Wl2 : Wr2;
            const int nn = (n < 128) ? n : n - 128;
            W2t[id] = __float2half(W[(size_t)k * 128 + nn]);
        }
    } else {
        const int i = (b - CVT_BLOCKS) * 256 + threadIdx.x;
        if (i < E_EDGES) {
            const int r = atomicAdd(&deg[dst[i]], 1);
            erank[i] = r;
        }
    }
}

// ---------------------------------------------------------------------------
// Two-phase parallel scan (R11 proven).
// ---------------------------------------------------------------------------
__global__ __launch_bounds__(256)
void scan_local(const int* __restrict__ deg, int* __restrict__ locpre,
                int* __restrict__ blockSum)
{
    const int i = blockIdx.x * 256 + threadIdx.x;
    const int lane = threadIdx.x & 63;
    const int wid = threadIdx.x >> 6;
    const int val = (i < N_NODES) ? deg[i] : 0;

    int v = val;
    #pragma unroll
    for (int off = 1; off < 64; off <<= 1) {
        int t = __shfl_up(v, off, 64);
        if (lane >= off) v += t;
    }
    __shared__ int ws[4];
    if (lane == 63) ws[wid] = v;
    __syncthreads();
    int woff = 0;
    for (int k = 0; k < wid; ++k) woff += ws[k];
    if (i < N_NODES) locpre[i] = woff + v - val;
    if (threadIdx.x == 255) blockSum[blockIdx.x] = woff + v;
}

__global__ __launch_bounds__(256)
void scan_final(const int* __restrict__ locpre, const int* __restrict__ blockSum,
                int* __restrict__ rowptr)
{
    const int b = blockIdx.x;
    const int t = threadIdx.x;
    int v = (t < b) ? blockSum[t] : 0;          // NB_SCAN(=196) < 256
    #pragma unroll
    for (int off = 32; off; off >>= 1) v += __shfl_xor(v, off, 64);
    __shared__ int ws[4];
    if ((t & 63) == 0) ws[t >> 6] = v;
    __syncthreads();
    const int offset = ws[0] + ws[1] + ws[2] + ws[3];

    const int i = b * 256 + t;
    if (i < N_NODES)
        rowptr[i] = locpre[i] + offset;
    if (b == 0 && t == 0) rowptr[N_NODES] = E_EDGES;
}

// ---------------------------------------------------------------------------
// R18: atomic-free scatter. pos = rowptr[dst] + rank (rank recorded in the
// histogram pass). rowptr is 200 KB -> L2-resident gather.
// ---------------------------------------------------------------------------
__global__ __launch_bounds__(256)
void scatter_edges(const int* __restrict__ src, const int* __restrict__ dst,
                   const int* __restrict__ rowptr, const int* __restrict__ erank,
                   int* __restrict__ ssrc, int E)
{
    int i = blockIdx.x * blockDim.x + threadIdx.x;
    if (i < E) {
        const int pos = rowptr[dst[i]] + erank[i];
        ssrc[pos] = src[i];
    }
}

// ---------------------------------------------------------------------------
// Layer-1 aggregation (H=4, C=64) — R17 shape: 8-edge unroll, pk-fp32
// accumulate, scalar CSR path (readfirstlane), DPP row reduce, exp2.
// Pinned at ~63 us by the L2-miss gather pipe (3.45 TB/s invariant R16-R19).
// ---------------------------------------------------------------------------
__global__ __launch_bounds__(256)
void agg1(const __half* __restrict__ xlr, const int* __restrict__ rowptr,
          const int* __restrict__ ssrc, const float* __restrict__ att,
          const float* __restrict__ b, __half* __restrict__ h)
{
    const int w = __builtin_amdgcn_readfirstlane(
        (int)((blockIdx.x * blockDim.x + threadIdx.x) >> 6));
    if (w >= N_NODES) return;
    const int lane = threadIdx.x & 63;
    const int ch = lane * 4;

    const float4 atf = *(const float4*)(att + ch);
    const h2f at0 = cvt_h2(atf.x * LOG2E, atf.y * LOG2E);
    const h2f at1 = cvt_h2(atf.z * LOG2E, atf.w * LOG2E);
    const float4 bb = *(const float4*)(b + ch);
    union { uint2 u; h2f v[2]; } R;
    R.u = *(const uint2*)(xlr + (size_t)w * 512 + 256 + ch);
    const h2f r0 = R.v[0], r1 = R.v[1];

    f32x2 a01 = {0.f, 0.f}, a23 = {0.f, 0.f};
    f32x2 den2 = {0.f, 0.f};

    const int beg = rowptr[w], end = rowptr[w + 1];
    int i = beg;
    while (i + 8 <= end) {
        union { uint2 u; h2f v[2]; } U[8];
        #pragma unroll
        for (int j = 0; j < 8; ++j) {
            const int s = ssrc[i + j];
            U[j].u = *(const uint2*)(xlr + (size_t)s * 512 + ch);
        }
        float m[8];
        #pragma unroll
        for (int j = 0; j < 8; ++j) {
            m[j] = dot2acc(leaky2(U[j].v[0] + r0), at0, 0.f);
            m[j] = dot2acc(leaky2(U[j].v[1] + r1), at1, m[j]);
        }
        #pragma unroll
        for (int j = 0; j < 8; ++j)
            m[j] = red16(m[j]);
        float e[8];
        #pragma unroll
        for (int j = 0; j < 8; ++j)
            e[j] = exp2f(m[j]);
        #pragma unroll
        for (int j = 0; j < 8; j += 2) {
            f32x2 ep = {e[j], e[j + 1]};
            den2 += ep;
        }
        #pragma unroll
        for (int j = 0; j < 8; ++j) {
            const f32x2 ee = {e[j], e[j]};
            a01 += ee * cvt2f(U[j].v[0]);
            a23 += ee * cvt2f(U[j].v[1]);
        }
        i += 8;
    }
    while (i + 4 <= end) {
        union { uint2 u; h2f v[2]; } U[4];
        #pragma unroll
        for (int j = 0; j < 4; ++j) {
            const int s = ssrc[i + j];
            U[j].u = *(const uint2*)(xlr + (size_t)s * 512 + ch);
        }
        float m[4];
        #pragma unroll
        for (int j = 0; j < 4; ++j) {
            m[j] = dot2acc(leaky2(U[j].v[0] + r0), at0, 0.f);
            m[j] = dot2acc(leaky2(U[j].v[1] + r1), at1, m[j]);
        }
        #pragma unroll
        for (int j = 0; j < 4; ++j)
            m[j] = red16(m[j]);
        float e[4];
        #pragma unroll
        for (int j = 0; j < 4; ++j)
            e[j] = exp2f(m[j]);
        den2 += (f32x2){e[0], e[1]};
        den2 += (f32x2){e[2], e[3]};
        #pragma unroll
        for (int j = 0; j < 4; ++j) {
            const f32x2 ee = {e[j], e[j]};
            a01 += ee * cvt2f(U[j].v[0]);
            a23 += ee * cvt2f(U[j].v[1]);
        }
        i += 4;
    }
    while (i < end) {
        const int s = ssrc[i];
        union { uint2 u; h2f v[2]; } U;
        U.u = *(const uint2*)(xlr + (size_t)s * 512 + ch);
        float m = dot2acc(leaky2(U.v[0] + r0), at0, 0.f);
        m = dot2acc(leaky2(U.v[1] + r1), at1, m);
        m = red16(m);
        const float e = exp2f(m);
        den2[0] += e;
        const f32x2 ee = {e, e};
        a01 += ee * cvt2f(U.v[0]);
        a23 += ee * cvt2f(U.v[1]);
        ++i;
    }

    const float den = den2[0] + den2[1];
    const float inv = 1.f / (den + EPS);
    float v0 = a01[0] * inv + bb.x;
    float v1 = a01[1] * inv + bb.y;
    float v2 = a23[0] * inv + bb.z;
    float v3 = a23[1] * inv + bb.w;
    v0 = v0 > 0.f ? v0 : __expf(v0) - 1.f;
    v1 = v1 > 0.f ? v1 : __expf(v1) - 1.f;
    v2 = v2 > 0.f ? v2 : __expf(v2) - 1.f;
    v3 = v3 > 0.f ? v3 : __expf(v3) - 1.f;
    union { uint2 u; __half2 h2[2]; } O;
    O.h2[0] = __floats2half2_rn(v0, v1);
    O.h2[1] = __floats2half2_rn(v2, v3);
    *(uint2*)(h + (size_t)w * 256 + ch) = O.u;
}

// ---------------------------------------------------------------------------
// Layer-2 aggregation (H=1, C=128) — R20 restructure: 4 independent 16-lane
// groups, one edge per group. Lane owns 8 ch -> one uint4 (16 B) load per
// edge (half the load instrs), score reduce is red16 ONLY (DPP rows align
// with groups; the per-edge shfl_xor(16) is gone). 2-edge unroll per group
// = 8 outstanding 16 B gathers/wave. Cross-group combine once per node.
// ---------------------------------------------------------------------------
__global__ __launch_bounds__(256)
void agg2(const __half* __restrict__ xlr, const int* __restrict__ rowptr,
          const int* __restrict__ ssrc, const float* __restrict__ att,
          const float* __restrict__ b, float* __restrict__ out)
{
    const int w = __builtin_amdgcn_readfirstlane(
        (int)((blockIdx.x * blockDim.x + threadIdx.x) >> 6));
    if (w >= N_NODES) return;
    const int lane = threadIdx.x & 63;
    const int g = lane >> 4;           // edge group 0..3
    const int ch = (lane & 15) * 8;    // 8 channels per lane

    const float4 atfa = *(const float4*)(att + ch);
    const float4 atfb = *(const float4*)(att + ch + 4);
    const h2f at0 = cvt_h2(atfa.x * LOG2E, atfa.y * LOG2E);
    const h2f at1 = cvt_h2(atfa.z * LOG2E, atfa.w * LOG2E);
    const h2f at2 = cvt_h2(atfb.x * LOG2E, atfb.y * LOG2E);
    const h2f at3 = cvt_h2(atfb.z * LOG2E, atfb.w * LOG2E);

    union { uint4 u; h2f v[4]; } R;
    R.u = *(const uint4*)(xlr + (size_t)w * 256 + 128 + ch);
    const h2f r0 = R.v[0], r1 = R.v[1], r2 = R.v[2], r3 = R.v[3];

    f32x2 a0 = {0.f, 0.f}, a1 = {0.f, 0.f}, a2 = {0.f, 0.f}, a3 = {0.f, 0.f};
    float den = 0.f;

    const int beg = rowptr[w], end = rowptr[w + 1];
    int i = beg + g;
    while (i + 4 < end) {                 // two edges: i and i+4
        union { uint4 u; h2f v[4]; } U[2];
        const int s0 = ssrc[i];
        const int s1 = ssrc[i + 4];
        U[0].u = *(const uint4*)(xlr + (size_t)s0 * 256 + ch);
        U[1].u = *(const uint4*)(xlr + (size_t)s1 * 256 + ch);
        float m[2];
        #pragma unroll
        for (int j = 0; j < 2; ++j) {
            float mm = dot2acc(leaky2(U[j].v[0] + r0), at0, 0.f);
            mm = dot2acc(leaky2(U[j].v[1] + r1), at1, mm);
            mm = dot2acc(leaky2(U[j].v[2] + r2), at2, mm);
            mm = dot2acc(leaky2(U[j].v[3] + r3), at3, mm);
            m[j] = red16(mm);
        }
        #pragma unroll
        for (int j = 0; j < 2; ++j) {
            const float e = exp2f(m[j]);
            den += e;
            const f32x2 ee = {e, e};
            a0 += ee * cvt2f(U[j].v[0]);
            a1 += ee * cvt2f(U[j].v[1]);
            a2 += ee * cvt2f(U[j].v[2]);
            a3 += ee * cvt2f(U[j].v[3]);
        }
        i += 8;
    }
    while (i < end) {                      // 0..2 residual edges per group
        const int s = ssrc[i];
        union { uint4 u; h2f v[4]; } U;
        U.u = *(const uint4*)(xlr + (size_t)s * 256 + ch);
        float mm = dot2acc(leaky2(U.v[0] + r0), at0, 0.f);
        mm = dot2acc(leaky2(U.v[1] + r1), at1, mm);
        mm = dot2acc(leaky2(U.v[2] + r2), at2, mm);
        mm = dot2acc(leaky2(U.v[3] + r3), at3, mm);
        const float e = exp2f(red16(mm));
        den += e;
        const f32x2 ee = {e, e};
        a0 += ee * cvt2f(U.v[0]);
        a1 += ee * cvt2f(U.v[1]);
        a2 += ee * cvt2f(U.v[2]);
        a3 += ee * cvt2f(U.v[3]);
        i += 4;
    }

    // cross-group combine (once per node): lanes differing in bits 4,5
    #pragma unroll
    for (int off = 16; off <= 32; off <<= 1) {
        a0[0] += __shfl_xor(a0[0], off, 64);
        a0[1] += __shfl_xor(a0[1], off, 64);
        a1[0] += __shfl_xor(a1[0], off, 64);
        a1[1] += __shfl_xor(a1[1], off, 64);
        a2[0] += __shfl_xor(a2[0], off, 64);
        a2[1] += __shfl_xor(a2[1], off, 64);
        a3[0] += __shfl_xor(a3[0], off, 64);
        a3[1] += __shfl_xor(a3[1], off, 64);
        den += __shfl_xor(den, off, 64);
    }

    if (lane < 16) {
        const float4 bba = *(const float4*)(b + ch);
        const float4 bbb = *(const float4*)(b + ch + 4);
        const float inv = 1.f / (den + EPS);
        float4 o1, o2;
        o1.x = a0[0] * inv + bba.x;
        o1.y = a0[1] * inv + bba.y;
        o1.z = a1[0] * inv + bba.z;
        o1.w = a1[1] * inv + bba.w;
        o2.x = a2[0] * inv + bbb.x;
        o2.y = a2[1] * inv + bbb.y;
        o2.z = a3[0] * inv + bbb.z;
        o2.w = a3[1] * inv + bbb.w;
        *(float4*)(out + (size_t)w * 128 + ch) = o1;
        *(float4*)(out + (size_t)w * 128 + ch + 4) = o2;
    }
}

extern "C" void kernel_launch(void* const* d_in, const int* in_sizes, int n_in,
                              void* d_out, int out_size, void* d_ws, size_t ws_size,
                              hipStream_t stream)
{
    const float* x    = (const float*)d_in[0];
    const int*   ei   = (const int*)d_in[1];
    const float* Wl1  = (const float*)d_in[2];
    const float* Wr1  = (const float*)d_in[3];
    const float* att1 = (const float*)d_in[4];
    const float* b1   = (const float*)d_in[5];
    const float* Wl2  = (const float*)d_in[6];
    const float* Wr2  = (const float*)d_in[7];
    const float* att2 = (const float*)d_in[8];
    const float* b2   = (const float*)d_in[9];
    const int* src = ei;
    const int* dst = ei + E_EDGES;
    float* out = (float*)d_out;

    // Workspace layout (fp16 unless noted):
    //   xlr1 [N,512] = [xl1|xr1]   (51.2 MB); reused as xlr2 [N,256]
    //   hh   [N,256]  — ALSO overlaid as erank[E] (lifetimes disjoint:
    //                   erank dies at scatter_edges; hh born at agg1)
    //   W1t  [512,128], W2t [256,256]
    //   ints: rowptr[N+1], deg[N], ssrc[E], locpre[N], blockSum[NB]
    __half* xlr1 = (__half*)d_ws;
    __half* hh   = xlr1 + (size_t)N_NODES * 512;
    __half* W1t  = hh + (size_t)N_NODES * 256;
    __half* W2t  = W1t + 512 * 128;
    int* rowptr   = (int*)(W2t + 256 * 256);
    int* deg      = rowptr + (N_NODES + 1);
    int* ssrc     = deg + N_NODES;
    int* locpre   = ssrc + E_EDGES;
    int* blockSum = locpre + N_NODES;
    int* erank    = (int*)hh;           // overlay, 3.2 MB < 25.6 MB
    __half* xlr2 = xlr1;

    const dim3 blk(256);
    const int hist_blocks = (E_EDGES + 255) / 256;

    // --- zero deg ---
    hipMemsetAsync(deg, 0, (size_t)N_NODES * 4, stream);

    // --- weight convert + dst histogram w/ rank record ---
    cvt_and_hist<<<CVT_BLOCKS + hist_blocks, blk, 0, stream>>>(
        Wl1, Wr1, Wl2, Wr2, W1t, W2t, dst, deg, erank);

    // --- two-phase scan (R11 proven) ---
    scan_local<<<NB_SCAN, blk, 0, stream>>>(deg, locpre, blockSum);
    scan_final<<<NB_SCAN, blk, 0, stream>>>(locpre, blockSum, rowptr);

    // --- atomic-free edge scatter ---
    scatter_edges<<<hist_blocks, blk, 0, stream>>>(src, dst, rowptr, erank, ssrc, E_EDGES);

    // --- Layer 1: [N,128] @ [128,512] (fused Wl|Wr), 128x256 tiles, BK=32 ---
    gemm_mfma<float><<<dim3(GX1, 2), blk, 0, stream>>>(x, W1t, xlr1, N_NODES, 128, 512);
    agg1<<<(N_NODES * 64 + 255) / 256, blk, 0, stream>>>(xlr1, rowptr, ssrc, att1, b1, hh);

    // --- Layer 2: [N,256] @ [256,256] (fused Wl|Wr), 128x256 tiles, BK=32 ---
    gemm_mfma<_Float16><<<dim3(GX1, 1), blk, 0, stream>>>((const _Float16*)hh, W2t, xlr2, N_NODES, 256, 256);
    agg2<<<(N_NODES * 64 + 255) / 256, blk, 0, stream>>>(xlr2, rowptr, ssrc, att2, b2, out);
}